// Round 7
// baseline (154.893 us; speedup 1.0000x reference)
//
#include <hip/hip_runtime.h>

#define BATCH 8
#define NPTS  1024
#define FH    256
#define FW    256
#define FC    256
#define HID   512
#define PADN  1056          // 16-row halo each side (rate <= 9)
#define HALO  16

typedef __attribute__((ext_vector_type(8))) short short8;
typedef __attribute__((ext_vector_type(16))) float f32x16;
typedef unsigned short ushort_t;
typedef unsigned int uint_t;

__device__ __forceinline__ ushort_t f2bf(float f) {
    uint_t u = __builtin_bit_cast(uint_t, f);
    u += 0x7fffu + ((u >> 16) & 1u);          // round-to-nearest-even
    return (ushort_t)(u >> 16);
}
__device__ __forceinline__ float bf2f(ushort_t s) {
    uint_t u = ((uint_t)s) << 16;
    return __builtin_bit_cast(float, u);
}

#define GLOAD16(g, l)                                                     \
    __builtin_amdgcn_global_load_lds(                                     \
        (const __attribute__((address_space(1))) void*)(g),               \
        (__attribute__((address_space(3))) void*)(l), 16, 0, 0)

// ---------------------------------------------------------------------------
// Fused prep kernel: [0,1280) halo zeroing, [1280,2336) weight transform into
// MFMA-fragment order, [2336,4384) bilinear sampling (4 vertices per block).
//
// Fragment-ordered weights: block (gco, s) of 512 shorts (1 KB), gco = co/32,
// s = k/16 (k = tap*CIN+ci).  Element at short-offset l*8 + j holds
// w[k = s*16 + (l>>5)*8 + j][co = gco*32 + (l&31)]  -- exactly lane l's
// 16-byte B fragment for mfma_f32_32x32x16_bf16.  One coalesced
// global_load_dwordx4 per wave = one B fragment.
// ---------------------------------------------------------------------------
__global__ __launch_bounds__(256) void prep_kernel(
    const float* __restrict__ vertices, const float* __restrict__ features,
    const float* __restrict__ w0, const float* __restrict__ w1,
    const float* __restrict__ w2, const float* __restrict__ w3,
    const float* __restrict__ w4, const float* __restrict__ w5,
    ushort_t* __restrict__ wt0, ushort_t* __restrict__ wt1,
    ushort_t* __restrict__ wt2, ushort_t* __restrict__ wt3,
    ushort_t* __restrict__ wt4, ushort_t* __restrict__ wt5,
    ushort_t* __restrict__ XpA, ushort_t* __restrict__ XpB,
    ushort_t* __restrict__ XpC)
{
    __shared__ float tile[64][65];
    const int blk = blockIdx.x;
    const int tid = threadIdx.x;

    if (blk < 1280) {
        // ---- halo zeroing ----
        int i = blk * 256 + tid;
        if (i < 65536) {                   // A halos: 8 * 2 strips * 16*256
            int b = i >> 13, rem = i & 8191;
            int strip = rem >> 12, off = rem & 4095;
            XpA[(size_t)b * (PADN * FC) + (strip ? (PADN - HALO) * FC : 0) + off] = 0;
        }
        int jB = i - 65536;                // B,C halos: 8 * 2 strips * 16*512
        if (jB >= 0 && jB < 262144) {
            ushort_t* T = (jB < 131072) ? XpB : XpC;
            int j = jB & 131071;
            int b = j >> 14, rem = j & 16383;
            int strip = rem >> 13, off = rem & 8191;
            T[(size_t)b * (PADN * HID) + (strip ? (PADN - HALO) * HID : 0) + off] = 0;
        }
        return;
    }

    if (blk < 2336) {
        // ---- weight transform: w [3][CIN][512] fp32 -> fragment-ordered bf16 ----
        int j = blk - 1280;
        const float* w; ushort_t* wt; int CIN, kk0, co0;
        if (j < 96) {
            w = w0; wt = wt0; CIN = FC;
            kk0 = (j % 12) * 64; co0 = (j / 12) * 64;
        } else {
            int j2 = j - 96;
            int layer = j2 / 192, jj = j2 % 192;
            const float* ws[5]  = {w1, w2, w3, w4, w5};
            ushort_t*   wts[5]  = {wt1, wt2, wt3, wt4, wt5};
            w = ws[layer]; wt = wts[layer]; CIN = HID;
            kk0 = (jj % 24) * 64; co0 = (jj / 24) * 64;
        }
        int tap = kk0 / CIN, ci0 = kk0 - tap * CIN;
        int SL  = (3 * CIN) >> 4;          // k-slices total
        // stage tile[k_local][co_local]
#pragma unroll 4
        for (int it = 0; it < 16; ++it) {
            int r = it * 4 + (tid >> 6);
            tile[r][tid & 63] = w[((size_t)tap * CIN + ci0 + r) * HID + co0 + (tid & 63)];
        }
        __syncthreads();
        // emit fragment blocks
        int gl  = tid >> 7;                // 0..1: co-group within 64-co panel
        int r2  = tid & 127;
        int l   = r2 >> 1;                 // lane 0..63
        int j0  = (r2 & 1) * 4;
        int gco = (co0 >> 5) + gl;
        int kb  = ((l >> 5) << 3);         // k base within slice from lane
        int cl  = gl * 32 + (l & 31);      // co_local
#pragma unroll
        for (int si = 0; si < 4; ++si) {
            int s = (kk0 >> 4) + si;
            ushort4 v;
            v.x = f2bf(tile[si * 16 + kb + j0 + 0][cl]);
            v.y = f2bf(tile[si * 16 + kb + j0 + 1][cl]);
            v.z = f2bf(tile[si * 16 + kb + j0 + 2][cl]);
            v.w = f2bf(tile[si * 16 + kb + j0 + 3][cl]);
            *(ushort4*)(wt + ((((size_t)gco * SL) + s) << 9) + l * 8 + j0) = v;
        }
        return;
    }

    // ---- bilinear sampling: 4 vertices per block ----
    {
        int p = (blk - 2336) * 4 + (tid >> 6);   // b*NPTS + n
        int b = p >> 10;
        int n = p & 1023;
        int t = tid & 63;                        // 4 channels each

        float y = vertices[2 * p + 0];
        float x = vertices[2 * p + 1];
        float y0f = floorf(y), x0f = floorf(x);
        float wy1 = y - y0f, wx1 = x - x0f;
        float wy0 = 1.f - wy1, wx0 = 1.f - wx1;
        int y0 = (int)y0f, x0 = (int)x0f;

        float4 acc = make_float4(0.f, 0.f, 0.f, 0.f);
        const float4* fbase = (const float4*)features + (size_t)b * FH * FW * (FC / 4);

#define CORNER(yi, xi, wgt) {                                                  \
        int yy = (yi), xx = (xi);                                              \
        float wv = ((yy >= 0) && (yy < FH) && (xx >= 0) && (xx < FW)) ? (wgt) : 0.f; \
        int yc = yy < 0 ? 0 : (yy > FH - 1 ? FH - 1 : yy);                     \
        int xc = xx < 0 ? 0 : (xx > FW - 1 ? FW - 1 : xx);                     \
        float4 v = fbase[((size_t)yc * FW + xc) * (FC / 4) + t];               \
        acc.x += v.x * wv; acc.y += v.y * wv; acc.z += v.z * wv; acc.w += v.w * wv; }

        CORNER(y0,     x0,     wy0 * wx0);
        CORNER(y0,     x0 + 1, wy0 * wx1);
        CORNER(y0 + 1, x0,     wy1 * wx0);
        CORNER(y0 + 1, x0 + 1, wy1 * wx1);
#undef CORNER

        ushort4 o;
        o.x = f2bf(acc.x); o.y = f2bf(acc.y); o.z = f2bf(acc.z); o.w = f2bf(acc.w);
        *(ushort4*)(XpA + ((size_t)b * PADN + HALO + n) * FC + 4 * t) = o;
    }
}

// ---------------------------------------------------------------------------
// Dilated conv as MFMA GEMM, tile 128x64 (M x CO), EIGHT waves (4x2),
// wave tile 32x32 -> 4 waves/SIMD at 2 blocks/CU (double all prior rounds).
// A: LDS, triple-buffered 16 KB tiles, prefetch depth 2 (2 gloads/wave/kt).
// B: direct L2->regs (fragment-ordered), double reg set (4 loads/wave/kt).
// Per wave per kt: 4 ds_read + 4 MFMA; vmcnt(2) invariant retires A(kt)+B(kt)
// leaving A(kt+1) in flight.  One raw barrier per kt + sched_barrier fence.
// Grid 512, XCD decode: the 8 co-blocks of one m-panel share one XCD.
// ---------------------------------------------------------------------------
template <int CIN>
__global__ __launch_bounds__(512, 4) void conv_mfma(
    const ushort_t* __restrict__ Xp,   // [8][1056][CIN] bf16
    const ushort_t* __restrict__ Wf,   // fragment-ordered weights
    const float* __restrict__ bias,    // [512] fp32
    ushort_t* __restrict__ Yp,         // [8][1056][512] bf16 (interior write)
    int rate)
{
    constexpr int K3 = 3 * CIN;
    constexpr int NT = K3 / 64;        // K-steps (even: 12 or 24)
    constexpr int SL = K3 / 16;        // k-slices
    __shared__ short lds[3][8192];     // 3 x 16 KB A tiles

    const int tid  = threadIdx.x;
    const int wid  = tid >> 6;         // 0..7
    const int lane = tid & 63;
    const int wm   = wid >> 1;         // 0..3  (M rows of 32)
    const int wn   = wid & 1;          // 0..1  (CO cols of 32)

    const int h  = blockIdx.x;               // 0..511
    const int bm = (h & 7) * 8 + (h >> 6);   // 0..63  (XCD h%8 owns 8 m-panels)
    const int bn = (h >> 3) & 7;             // 0..7
    const int batch = bm >> 3;
    const int n0    = (bm & 7) * 128;
    const int co0   = bn * 64;

    const short* Xbase = (const short*)Xp + ((size_t)batch * PADN + HALO + n0) * CIN;
    const short* Wb = (const short*)Wf
                    + (((size_t)(bn * 2 + wn) * SL) << 9) + lane * 8;

    // ---- A staging: one K-step = A[128][64] bf16 = 16 KB, 2 gloads/wave ----
    auto stageA = [&](int buf, int kt) {
        const int tap = (kt << 6) / CIN;
        const int ci0 = (kt << 6) - tap * CIN;
        const short* Ag = Xbase + (ptrdiff_t)(tap - 1) * rate * CIN + ci0;
        short* ldsA = &lds[buf][0];
#pragma unroll
        for (int it = 0; it < 2; ++it) {
            int row  = wid * 16 + it * 8 + (lane >> 3);
            int chnk = (lane & 7) ^ (row & 7);    // inverse swizzle on src
            GLOAD16(Ag + (size_t)row * CIN + chnk * 8, ldsA + ((wid * 2 + it) << 9));
        }
    };
    // ---- B fragments for one K-step: 4 coalesced 16B loads into regs ----
    auto loadB = [&](short8* dst, int kt) {
        const short* p = Wb + ((size_t)(kt * 4) << 9);
#pragma unroll
        for (int ks = 0; ks < 4; ++ks) dst[ks] = *(const short8*)(p + (ks << 9));
    };

    // ---- accumulator init with bias ----
    f32x16 acc;
    const int rowA0 = wm * 32 + (lane & 31);
    const int coB   = wn * 32 + (lane & 31);
    {
        float bv = bias[co0 + coB];
#pragma unroll
        for (int r = 0; r < 16; ++r) acc[r] = bv;
    }

    short8 B0[4], B1[4];
    stageA(0, 0);
    loadB(B0, 0);
    stageA(1, 1);

    int cur = 0;                                  // buf of current K-step
    auto kstep = [&](int s, short8* Bcur, short8* Bnxt) {
        if (s == NT - 1) asm volatile("s_waitcnt vmcnt(0)" ::: "memory");
        else             asm volatile("s_waitcnt vmcnt(2)" ::: "memory");
        __builtin_amdgcn_s_barrier();
        __builtin_amdgcn_sched_barrier(0);        // fence: no hoist above barrier

        if (s + 1 < NT) loadB(Bnxt, s + 1);
        if (s + 2 < NT) {
            int nb = cur + 2; if (nb >= 3) nb -= 3;
            stageA(nb, s + 2);
        }

        const short* As = &lds[cur][0];
        __builtin_amdgcn_s_setprio(1);
#pragma unroll
        for (int ks = 0; ks < 4; ++ks) {
            int ch = ks * 2 + (lane >> 5);
            short8 av = *(const short8*)(As + rowA0 * 64 + ((ch ^ (rowA0 & 7)) << 3));
            acc = __builtin_amdgcn_mfma_f32_32x32x16_bf16(av, Bcur[ks], acc, 0, 0, 0);
        }
        __builtin_amdgcn_s_setprio(0);
        cur += 1; if (cur >= 3) cur -= 3;
    };

    for (int kt = 0; kt < NT; kt += 2) {
        kstep(kt,     B0, B1);
        kstep(kt + 1, B1, B0);
    }

    // ---- epilogue: ReLU + bf16 store into padded interior ----
    ushort_t* Yb = Yp + ((size_t)batch * PADN + HALO + n0) * HID + co0;
#pragma unroll
    for (int r = 0; r < 16; ++r) {
        int rrow = wm * 32 + (r & 3) + 8 * (r >> 2) + 4 * (lane >> 5);
        float v = acc[r];
        v = v > 0.f ? v : 0.f;
        Yb[(size_t)rrow * HID + coB] = f2bf(v);
    }
}

// ---------------------------------------------------------------------------
// Offset head: out[p,:] = vertices[p,:] + h[p,:] @ w_off  (bf16 h, fp32 w)
// ---------------------------------------------------------------------------
__global__ __launch_bounds__(64) void head_kernel(
    const ushort_t* __restrict__ h, const float* __restrict__ w_off,
    const float* __restrict__ vertices, float* __restrict__ out)
{
    int p = blockIdx.x;
    int b = p >> 10, n = p & 1023;
    int t = threadIdx.x;
    const ushort_t* hr = h + ((size_t)b * PADN + HALO + n) * HID + t * 8;

    uint4 raw = *(const uint4*)hr;
    ushort_t hv[8];
    hv[0] = raw.x & 0xffff; hv[1] = raw.x >> 16;
    hv[2] = raw.y & 0xffff; hv[3] = raw.y >> 16;
    hv[4] = raw.z & 0xffff; hv[5] = raw.z >> 16;
    hv[6] = raw.w & 0xffff; hv[7] = raw.w >> 16;

    float s0 = 0.f, s1 = 0.f;
#pragma unroll
    for (int k = 0; k < 8; ++k) {
        float x = bf2f(hv[k]);
        s0 += x * w_off[(t * 8 + k) * 2 + 0];
        s1 += x * w_off[(t * 8 + k) * 2 + 1];
    }
#pragma unroll
    for (int off = 32; off >= 1; off >>= 1) {
        s0 += __shfl_down(s0, off);
        s1 += __shfl_down(s1, off);
    }
    if (t == 0) {
        out[2 * p + 0] = vertices[2 * p + 0] + s0;
        out[2 * p + 1] = vertices[2 * p + 1] + s1;
    }
}

// ---------------------------------------------------------------------------
extern "C" void kernel_launch(void* const* d_in, const int* in_sizes, int n_in,
                              void* d_out, int out_size, void* d_ws, size_t ws_size,
                              hipStream_t stream)
{
    (void)in_sizes; (void)n_in; (void)out_size; (void)ws_size;

    const float* vertices = (const float*)d_in[0];
    const float* features = (const float*)d_in[1];
    const float* w[6]  = {(const float*)d_in[2], (const float*)d_in[4],
                          (const float*)d_in[6], (const float*)d_in[8],
                          (const float*)d_in[10], (const float*)d_in[12]};
    const float* bb[6] = {(const float*)d_in[3], (const float*)d_in[5],
                          (const float*)d_in[7], (const float*)d_in[9],
                          (const float*)d_in[11], (const float*)d_in[13]};
    const float* w_off = (const float*)d_in[14];
    float* out = (float*)d_out;

    // ---- workspace layout ----
    char* p = (char*)d_ws;
    ushort_t* wt[6];
    wt[0] = (ushort_t*)p; p += (size_t)HID * (3 * FC) * 2;          // 768 KB
    for (int i = 1; i < 6; ++i) { wt[i] = (ushort_t*)p; p += (size_t)HID * (3 * HID) * 2; }
    ushort_t* XpA = (ushort_t*)p; p += (size_t)BATCH * PADN * FC  * 2;
    ushort_t* XpB = (ushort_t*)p; p += (size_t)BATCH * PADN * HID * 2;
    ushort_t* XpC = (ushort_t*)p;

    // ---- fused prep: halos + fragment-ordered weights + sampling ----
    prep_kernel<<<4384, 256, 0, stream>>>(
        vertices, features, w[0], w[1], w[2], w[3], w[4], w[5],
        wt[0], wt[1], wt[2], wt[3], wt[4], wt[5], XpA, XpB, XpC);

    // ---- conv stack (A -> B -> C -> B -> C -> B -> C) ----
    static const int rates[6] = {1, 3, 9, 9, 3, 1};
    conv_mfma<FC><<<512, 512, 0, stream>>>(XpA, wt[0], bb[0], XpB, rates[0]);
    ushort_t* src = XpB;
    ushort_t* dst = XpC;
    for (int i = 1; i < 6; ++i) {
        conv_mfma<HID><<<512, 512, 0, stream>>>(src, wt[i], bb[i], dst, rates[i]);
        ushort_t* tmp = src; src = dst; dst = tmp;
    }

    // ---- head ----
    head_kernel<<<BATCH * NPTS, 64, 0, stream>>>(src, w_off, vertices, out);
}

// Round 8
// 137.116 us; speedup vs baseline: 1.1297x; 1.1297x over previous
//
#include <hip/hip_runtime.h>

#define BATCH 8
#define NPTS  1024
#define FH    256
#define FW    256
#define FC    256
#define HID   512
#define PADN  1056          // 16-row halo each side (rate <= 9)
#define HALO  16

typedef __attribute__((ext_vector_type(8))) short short8;
typedef __attribute__((ext_vector_type(16))) float f32x16;
typedef unsigned short ushort_t;
typedef unsigned int uint_t;

__device__ __forceinline__ ushort_t f2bf(float f) {
    uint_t u = __builtin_bit_cast(uint_t, f);
    u += 0x7fffu + ((u >> 16) & 1u);          // round-to-nearest-even
    return (ushort_t)(u >> 16);
}
__device__ __forceinline__ float bf2f(ushort_t s) {
    uint_t u = ((uint_t)s) << 16;
    return __builtin_bit_cast(float, u);
}

#define GLOAD16(g, l)                                                     \
    __builtin_amdgcn_global_load_lds(                                     \
        (const __attribute__((address_space(1))) void*)(g),               \
        (__attribute__((address_space(3))) void*)(l), 16, 0, 0)

// Opaque LDS read: legalizer can't see the LDS dependency -> no auto vmcnt(0).
__device__ __forceinline__ short8 ldsread16(const short* p) {
    short8 r;
    const __attribute__((address_space(3))) short* p3 =
        (const __attribute__((address_space(3))) short*)p;
    asm volatile("ds_read_b128 %0, %1" : "=v"(r) : "v"(p3));
    return r;
}
// Opaque global->VGPR 16B load: keeps the per-wave vmcnt FIFO count exact.
__device__ __forceinline__ short8 gread16(const short* p) {
    short8 r;
    asm volatile("global_load_dwordx4 %0, %1, off" : "=v"(r) : "v"(p));
    return r;
}

// ---------------------------------------------------------------------------
// Fused prep kernel: [0,1280) halo zeroing, [1280,2336) weight transform into
// MFMA-fragment order, [2336,4384) bilinear sampling (4 vertices per block).
//
// Fragment-ordered weights: block (gco, s) of 512 shorts (1 KB), gco = co/32,
// s = k/16 (k = tap*CIN+ci).  Element at short-offset l*8 + j holds
// w[k = s*16 + (l>>5)*8 + j][co = gco*32 + (l&31)]  -- exactly lane l's
// 16-byte B fragment for mfma_f32_32x32x16_bf16.
// ---------------------------------------------------------------------------
__global__ __launch_bounds__(256) void prep_kernel(
    const float* __restrict__ vertices, const float* __restrict__ features,
    const float* __restrict__ w0, const float* __restrict__ w1,
    const float* __restrict__ w2, const float* __restrict__ w3,
    const float* __restrict__ w4, const float* __restrict__ w5,
    ushort_t* __restrict__ wt0, ushort_t* __restrict__ wt1,
    ushort_t* __restrict__ wt2, ushort_t* __restrict__ wt3,
    ushort_t* __restrict__ wt4, ushort_t* __restrict__ wt5,
    ushort_t* __restrict__ XpA, ushort_t* __restrict__ XpB,
    ushort_t* __restrict__ XpC)
{
    __shared__ float tile[64][65];
    const int blk = blockIdx.x;
    const int tid = threadIdx.x;

    if (blk < 1280) {
        // ---- halo zeroing ----
        int i = blk * 256 + tid;
        if (i < 65536) {                   // A halos: 8 * 2 strips * 16*256
            int b = i >> 13, rem = i & 8191;
            int strip = rem >> 12, off = rem & 4095;
            XpA[(size_t)b * (PADN * FC) + (strip ? (PADN - HALO) * FC : 0) + off] = 0;
        }
        int jB = i - 65536;                // B,C halos: 8 * 2 strips * 16*512
        if (jB >= 0 && jB < 262144) {
            ushort_t* T = (jB < 131072) ? XpB : XpC;
            int j = jB & 131071;
            int b = j >> 14, rem = j & 16383;
            int strip = rem >> 13, off = rem & 8191;
            T[(size_t)b * (PADN * HID) + (strip ? (PADN - HALO) * HID : 0) + off] = 0;
        }
        return;
    }

    if (blk < 2336) {
        // ---- weight transform: w [3][CIN][512] fp32 -> fragment-ordered bf16 ----
        int j = blk - 1280;
        const float* w; ushort_t* wt; int CIN, kk0, co0;
        if (j < 96) {
            w = w0; wt = wt0; CIN = FC;
            kk0 = (j % 12) * 64; co0 = (j / 12) * 64;
        } else {
            int j2 = j - 96;
            int layer = j2 / 192, jj = j2 % 192;
            const float* ws[5]  = {w1, w2, w3, w4, w5};
            ushort_t*   wts[5]  = {wt1, wt2, wt3, wt4, wt5};
            w = ws[layer]; wt = wts[layer]; CIN = HID;
            kk0 = (jj % 24) * 64; co0 = (jj / 24) * 64;
        }
        int tap = kk0 / CIN, ci0 = kk0 - tap * CIN;
        int SL  = (3 * CIN) >> 4;          // k-slices total
        // stage tile[k_local][co_local]
#pragma unroll 4
        for (int it = 0; it < 16; ++it) {
            int r = it * 4 + (tid >> 6);
            tile[r][tid & 63] = w[((size_t)tap * CIN + ci0 + r) * HID + co0 + (tid & 63)];
        }
        __syncthreads();
        // emit fragment blocks
        int gl  = tid >> 7;                // 0..1: co-group within 64-co panel
        int r2  = tid & 127;
        int l   = r2 >> 1;                 // lane 0..63
        int j0  = (r2 & 1) * 4;
        int gco = (co0 >> 5) + gl;
        int kb  = ((l >> 5) << 3);         // k base within slice from lane
        int cl  = gl * 32 + (l & 31);      // co_local
#pragma unroll
        for (int si = 0; si < 4; ++si) {
            int s = (kk0 >> 4) + si;
            ushort4 v;
            v.x = f2bf(tile[si * 16 + kb + j0 + 0][cl]);
            v.y = f2bf(tile[si * 16 + kb + j0 + 1][cl]);
            v.z = f2bf(tile[si * 16 + kb + j0 + 2][cl]);
            v.w = f2bf(tile[si * 16 + kb + j0 + 3][cl]);
            *(ushort4*)(wt + ((((size_t)gco * SL) + s) << 9) + l * 8 + j0) = v;
        }
        return;
    }

    // ---- bilinear sampling: 4 vertices per block ----
    {
        int p = (blk - 2336) * 4 + (tid >> 6);   // b*NPTS + n
        int b = p >> 10;
        int n = p & 1023;
        int t = tid & 63;                        // 4 channels each

        float y = vertices[2 * p + 0];
        float x = vertices[2 * p + 1];
        float y0f = floorf(y), x0f = floorf(x);
        float wy1 = y - y0f, wx1 = x - x0f;
        float wy0 = 1.f - wy1, wx0 = 1.f - wx1;
        int y0 = (int)y0f, x0 = (int)x0f;

        float4 acc = make_float4(0.f, 0.f, 0.f, 0.f);
        const float4* fbase = (const float4*)features + (size_t)b * FH * FW * (FC / 4);

#define CORNER(yi, xi, wgt) {                                                  \
        int yy = (yi), xx = (xi);                                              \
        float wv = ((yy >= 0) && (yy < FH) && (xx >= 0) && (xx < FW)) ? (wgt) : 0.f; \
        int yc = yy < 0 ? 0 : (yy > FH - 1 ? FH - 1 : yy);                     \
        int xc = xx < 0 ? 0 : (xx > FW - 1 ? FW - 1 : xx);                     \
        float4 v = fbase[((size_t)yc * FW + xc) * (FC / 4) + t];               \
        acc.x += v.x * wv; acc.y += v.y * wv; acc.z += v.z * wv; acc.w += v.w * wv; }

        CORNER(y0,     x0,     wy0 * wx0);
        CORNER(y0,     x0 + 1, wy0 * wx1);
        CORNER(y0 + 1, x0,     wy1 * wx0);
        CORNER(y0 + 1, x0 + 1, wy1 * wx1);
#undef CORNER

        ushort4 o;
        o.x = f2bf(acc.x); o.y = f2bf(acc.y); o.z = f2bf(acc.z); o.w = f2bf(acc.w);
        *(ushort4*)(XpA + ((size_t)b * PADN + HALO + n) * FC + 4 * t) = o;
    }
}

// ---------------------------------------------------------------------------
// Dilated conv as MFMA GEMM, tile 128x64 (M x CO), 4 waves (2x2),
// wave tile 64x32.  A: LDS, triple-buffered 16 KB tiles, prefetch depth 2.
// B: direct L2->regs (fragment-ordered), double reg set.
// ALL K-loop memory ops are inline asm (opaque to the memory legalizer) so
// the ONLY waits in the loop are our counted ones:
//   per-wave FIFO/kt: [A(s) 4][B(s) 4][A(s+1) 4] at entry -> vmcnt(4)
//   retires A(s)+B(s), leaves A(s+1) in flight.  lgkmcnt(0)+sched_barrier(0)
//   fences the ds_read->MFMA hazard (rule 18).  One raw barrier per kt.
// Grid 512, XCD decode: the 8 co-blocks of one m-panel share one XCD.
// ---------------------------------------------------------------------------
template <int CIN>
__global__ __launch_bounds__(256) void conv_mfma(
    const ushort_t* __restrict__ Xp,   // [8][1056][CIN] bf16
    const ushort_t* __restrict__ Wf,   // fragment-ordered weights
    const float* __restrict__ bias,    // [512] fp32
    ushort_t* __restrict__ Yp,         // [8][1056][512] bf16 (interior write)
    int rate)
{
    constexpr int K3 = 3 * CIN;
    constexpr int NT = K3 / 64;        // K-steps (12 or 24)
    constexpr int SL = K3 / 16;        // k-slices
    __shared__ short lds[3][8192];     // 3 x 16 KB A tiles

    const int tid  = threadIdx.x;
    const int wid  = tid >> 6;
    const int lane = tid & 63;
    const int wm   = wid >> 1, wn = wid & 1;

    const int h  = blockIdx.x;               // 0..511
    const int bm = (h & 7) * 8 + (h >> 6);   // 0..63  (XCD h%8 owns 8 m-panels)
    const int bn = (h >> 3) & 7;             // 0..7
    const int batch = bm >> 3;
    const int n0    = (bm & 7) * 128;
    const int co0   = bn * 64;

    const short* Xbase = (const short*)Xp + ((size_t)batch * PADN + HALO + n0) * CIN;
    const short* Wb = (const short*)Wf
                    + (((size_t)(bn * 2 + wn) * SL) << 9) + lane * 8;

    // ---- A staging: one K-step = A[128][64] bf16 = 16 KB, 4 gloads/wave ----
    auto stageA = [&](int buf, int kt) {
        const int tap = (kt << 6) / CIN;
        const int ci0 = (kt << 6) - tap * CIN;
        const short* Ag = Xbase + (ptrdiff_t)(tap - 1) * rate * CIN + ci0;
        short* ldsA = &lds[buf][0];
#pragma unroll
        for (int it = 0; it < 4; ++it) {
            int row  = wid * 32 + it * 8 + (lane >> 3);
            int chnk = (lane & 7) ^ (row & 7);    // inverse swizzle on src
            GLOAD16(Ag + (size_t)row * CIN + chnk * 8, ldsA + ((wid * 4 + it) << 9));
        }
    };
    // ---- B fragments for one K-step: 4 coalesced 16B asm loads into regs ----
    auto loadB = [&](short8* dst, int kt) {
        const short* p = Wb + ((size_t)(kt * 4) << 9);
#pragma unroll
        for (int ks = 0; ks < 4; ++ks) dst[ks] = gread16(p + (ks << 9));
    };

    // ---- accumulators init with bias ----
    f32x16 acc[2];
    const int rowA0 = wm * 64 + (lane & 31);
    const int coB   = wn * 32 + (lane & 31);
    {
        float bv = bias[co0 + coB];
#pragma unroll
        for (int i = 0; i < 2; ++i)
#pragma unroll
            for (int r = 0; r < 16; ++r) acc[i][r] = bv;
    }

    short8 B0[4], B1[4];
    stageA(0, 0);
    __builtin_amdgcn_sched_barrier(0);
    loadB(B0, 0);
    __builtin_amdgcn_sched_barrier(0);
    stageA(1, 1);
    __builtin_amdgcn_sched_barrier(0);

    int cur = 0;                                  // buf of current K-step
    auto kstep = [&](int s, short8* Bcur, short8* Bnxt) {
        if (s == NT - 1) asm volatile("s_waitcnt vmcnt(0)" ::: "memory");
        else             asm volatile("s_waitcnt vmcnt(4)" ::: "memory");
        __builtin_amdgcn_s_barrier();
        __builtin_amdgcn_sched_barrier(0);

        if (s + 1 < NT) loadB(Bnxt, s + 1);
        __builtin_amdgcn_sched_barrier(0);        // pin FIFO order: B then A-stage
        if (s + 2 < NT) {
            int nb = cur + 2; if (nb >= 3) nb -= 3;
            stageA(nb, s + 2);
        }
        __builtin_amdgcn_sched_barrier(0);

        // ---- 8 opaque ds_reads, then one lgkm drain, then MFMA cluster ----
        const short* As = &lds[cur][0];
        short8 av[2][4];
#pragma unroll
        for (int ks = 0; ks < 4; ++ks) {
            int ch = ks * 2 + (lane >> 5);
#pragma unroll
            for (int i = 0; i < 2; ++i) {
                int ra = rowA0 + i * 32;
                av[i][ks] = ldsread16(As + ra * 64 + ((ch ^ (ra & 7)) << 3));
            }
        }
        asm volatile("s_waitcnt lgkmcnt(0)" ::: "memory");
        __builtin_amdgcn_sched_barrier(0);        // rule 18: no MFMA hoist
        __builtin_amdgcn_s_setprio(1);
#pragma unroll
        for (int ks = 0; ks < 4; ++ks)
#pragma unroll
            for (int i = 0; i < 2; ++i)
                acc[i] = __builtin_amdgcn_mfma_f32_32x32x16_bf16(
                    av[i][ks], Bcur[ks], acc[i], 0, 0, 0);
        __builtin_amdgcn_s_setprio(0);
        cur += 1; if (cur >= 3) cur -= 3;
    };

    for (int kt = 0; kt < NT; kt += 2) {
        kstep(kt,     B0, B1);
        kstep(kt + 1, B1, B0);
    }

    // ---- epilogue: ReLU + bf16 store into padded interior ----
    ushort_t* Yb = Yp + ((size_t)batch * PADN + HALO + n0) * HID + co0;
#pragma unroll
    for (int i = 0; i < 2; ++i) {
#pragma unroll
        for (int r = 0; r < 16; ++r) {
            int rrow = wm * 64 + i * 32 + (r & 3) + 8 * (r >> 2) + 4 * (lane >> 5);
            float v = acc[i][r];
            v = v > 0.f ? v : 0.f;
            Yb[(size_t)rrow * HID + coB] = f2bf(v);
        }
    }
}

// ---------------------------------------------------------------------------
// Offset head: out[p,:] = vertices[p,:] + h[p,:] @ w_off  (bf16 h, fp32 w)
// ---------------------------------------------------------------------------
__global__ __launch_bounds__(64) void head_kernel(
    const ushort_t* __restrict__ h, const float* __restrict__ w_off,
    const float* __restrict__ vertices, float* __restrict__ out)
{
    int p = blockIdx.x;
    int b = p >> 10, n = p & 1023;
    int t = threadIdx.x;
    const ushort_t* hr = h + ((size_t)b * PADN + HALO + n) * HID + t * 8;

    uint4 raw = *(const uint4*)hr;
    ushort_t hv[8];
    hv[0] = raw.x & 0xffff; hv[1] = raw.x >> 16;
    hv[2] = raw.y & 0xffff; hv[3] = raw.y >> 16;
    hv[4] = raw.z & 0xffff; hv[5] = raw.z >> 16;
    hv[6] = raw.w & 0xffff; hv[7] = raw.w >> 16;

    float s0 = 0.f, s1 = 0.f;
#pragma unroll
    for (int k = 0; k < 8; ++k) {
        float x = bf2f(hv[k]);
        s0 += x * w_off[(t * 8 + k) * 2 + 0];
        s1 += x * w_off[(t * 8 + k) * 2 + 1];
    }
#pragma unroll
    for (int off = 32; off >= 1; off >>= 1) {
        s0 += __shfl_down(s0, off);
        s1 += __shfl_down(s1, off);
    }
    if (t == 0) {
        out[2 * p + 0] = vertices[2 * p + 0] + s0;
        out[2 * p + 1] = vertices[2 * p + 1] + s1;
    }
}

// ---------------------------------------------------------------------------
extern "C" void kernel_launch(void* const* d_in, const int* in_sizes, int n_in,
                              void* d_out, int out_size, void* d_ws, size_t ws_size,
                              hipStream_t stream)
{
    (void)in_sizes; (void)n_in; (void)out_size; (void)ws_size;

    const float* vertices = (const float*)d_in[0];
    const float* features = (const float*)d_in[1];
    const float* w[6]  = {(const float*)d_in[2], (const float*)d_in[4],
                          (const float*)d_in[6], (const float*)d_in[8],
                          (const float*)d_in[10], (const float*)d_in[12]};
    const float* bb[6] = {(const float*)d_in[3], (const float*)d_in[5],
                          (const float*)d_in[7], (const float*)d_in[9],
                          (const float*)d_in[11], (const float*)d_in[13]};
    const float* w_off = (const float*)d_in[14];
    float* out = (float*)d_out;

    // ---- workspace layout ----
    char* p = (char*)d_ws;
    ushort_t* wt[6];
    wt[0] = (ushort_t*)p; p += (size_t)HID * (3 * FC) * 2;          // 768 KB
    for (int i = 1; i < 6; ++i) { wt[i] = (ushort_t*)p; p += (size_t)HID * (3 * HID) * 2; }
    ushort_t* XpA = (ushort_t*)p; p += (size_t)BATCH * PADN * FC  * 2;
    ushort_t* XpB = (ushort_t*)p; p += (size_t)BATCH * PADN * HID * 2;
    ushort_t* XpC = (ushort_t*)p;

    // ---- fused prep: halos + fragment-ordered weights + sampling ----
    prep_kernel<<<4384, 256, 0, stream>>>(
        vertices, features, w[0], w[1], w[2], w[3], w[4], w[5],
        wt[0], wt[1], wt[2], wt[3], wt[4], wt[5], XpA, XpB, XpC);

    // ---- conv stack (A -> B -> C -> B -> C -> B -> C) ----
    static const int rates[6] = {1, 3, 9, 9, 3, 1};
    conv_mfma<FC><<<512, 256, 0, stream>>>(XpA, wt[0], bb[0], XpB, rates[0]);
    ushort_t* src = XpB;
    ushort_t* dst = XpC;
    for (int i = 1; i < 6; ++i) {
        conv_mfma<HID><<<512, 256, 0, stream>>>(src, wt[i], bb[i], dst, rates[i]);
        ushort_t* tmp = src; src = dst; dst = tmp;
    }

    // ---- head ----
    head_kernel<<<BATCH * NPTS, 64, 0, stream>>>(src, w_off, vertices, out);
}

// Round 9
// 121.893 us; speedup vs baseline: 1.2707x; 1.1249x over previous
//
#include <hip/hip_runtime.h>

#define BATCH 8
#define NPTS  1024
#define FH    256
#define FW    256
#define FC    256
#define HID   512
#define PADN  1056          // 16-row halo each side (rate <= 9)
#define HALO  16

typedef __attribute__((ext_vector_type(8))) short short8;
typedef __attribute__((ext_vector_type(16))) float f32x16;
typedef unsigned short ushort_t;
typedef unsigned int uint_t;

__device__ __forceinline__ ushort_t f2bf(float f) {
    uint_t u = __builtin_bit_cast(uint_t, f);
    u += 0x7fffu + ((u >> 16) & 1u);          // round-to-nearest-even
    return (ushort_t)(u >> 16);
}
__device__ __forceinline__ float bf2f(ushort_t s) {
    uint_t u = ((uint_t)s) << 16;
    return __builtin_bit_cast(float, u);
}

#define GLOAD16(g, l)                                                     \
    __builtin_amdgcn_global_load_lds(                                     \
        (const __attribute__((address_space(1))) void*)(g),               \
        (__attribute__((address_space(3))) void*)(l), 16, 0, 0)

// Opaque global->VGPR 16B load: keeps the per-wave vmcnt FIFO count exact.
__device__ __forceinline__ short8 gread16(const short* p) {
    short8 r;
    asm volatile("global_load_dwordx4 %0, %1, off" : "=v"(r) : "v"(p));
    return r;
}

// ---------------------------------------------------------------------------
// Fused prep kernel: [0,1280) halo zeroing, [1280,2336) weight transform into
// MFMA-fragment order, [2336,4384) bilinear sampling (4 vertices per block).
//
// Fragment-ordered weights: block (gco, s) of 512 shorts (1 KB), gco = co/32,
// s = k/16 (k = tap*CIN+ci).  Element at short-offset l*8 + j holds
// w[k = s*16 + (l>>5)*8 + j][co = gco*32 + (l&31)]  -- lane l's 16-byte B
// fragment for mfma_f32_32x32x16_bf16.
// ---------------------------------------------------------------------------
__global__ __launch_bounds__(256) void prep_kernel(
    const float* __restrict__ vertices, const float* __restrict__ features,
    const float* __restrict__ w0, const float* __restrict__ w1,
    const float* __restrict__ w2, const float* __restrict__ w3,
    const float* __restrict__ w4, const float* __restrict__ w5,
    ushort_t* __restrict__ wt0, ushort_t* __restrict__ wt1,
    ushort_t* __restrict__ wt2, ushort_t* __restrict__ wt3,
    ushort_t* __restrict__ wt4, ushort_t* __restrict__ wt5,
    ushort_t* __restrict__ XpA, ushort_t* __restrict__ XpB,
    ushort_t* __restrict__ XpC)
{
    __shared__ float tile[64][65];
    const int blk = blockIdx.x;
    const int tid = threadIdx.x;

    if (blk < 1280) {
        // ---- halo zeroing ----
        int i = blk * 256 + tid;
        if (i < 65536) {                   // A halos: 8 * 2 strips * 16*256
            int b = i >> 13, rem = i & 8191;
            int strip = rem >> 12, off = rem & 4095;
            XpA[(size_t)b * (PADN * FC) + (strip ? (PADN - HALO) * FC : 0) + off] = 0;
        }
        int jB = i - 65536;                // B,C halos: 8 * 2 strips * 16*512
        if (jB >= 0 && jB < 262144) {
            ushort_t* T = (jB < 131072) ? XpB : XpC;
            int j = jB & 131071;
            int b = j >> 14, rem = j & 16383;
            int strip = rem >> 13, off = rem & 8191;
            T[(size_t)b * (PADN * HID) + (strip ? (PADN - HALO) * HID : 0) + off] = 0;
        }
        return;
    }

    if (blk < 2336) {
        // ---- weight transform: w [3][CIN][512] fp32 -> fragment-ordered bf16 ----
        int j = blk - 1280;
        const float* w; ushort_t* wt; int CIN, kk0, co0;
        if (j < 96) {
            w = w0; wt = wt0; CIN = FC;
            kk0 = (j % 12) * 64; co0 = (j / 12) * 64;
        } else {
            int j2 = j - 96;
            int layer = j2 / 192, jj = j2 % 192;
            const float* ws[5]  = {w1, w2, w3, w4, w5};
            ushort_t*   wts[5]  = {wt1, wt2, wt3, wt4, wt5};
            w = ws[layer]; wt = wts[layer]; CIN = HID;
            kk0 = (jj % 24) * 64; co0 = (jj / 24) * 64;
        }
        int tap = kk0 / CIN, ci0 = kk0 - tap * CIN;
        int SL  = (3 * CIN) >> 4;          // k-slices total
        // stage tile[k_local][co_local]
#pragma unroll 4
        for (int it = 0; it < 16; ++it) {
            int r = it * 4 + (tid >> 6);
            tile[r][tid & 63] = w[((size_t)tap * CIN + ci0 + r) * HID + co0 + (tid & 63)];
        }
        __syncthreads();
        // emit fragment blocks
        int gl  = tid >> 7;                // 0..1: co-group within 64-co panel
        int r2  = tid & 127;
        int l   = r2 >> 1;                 // lane 0..63
        int j0  = (r2 & 1) * 4;
        int gco = (co0 >> 5) + gl;
        int kb  = ((l >> 5) << 3);         // k base within slice from lane
        int cl  = gl * 32 + (l & 31);      // co_local
#pragma unroll
        for (int si = 0; si < 4; ++si) {
            int s = (kk0 >> 4) + si;
            ushort4 v;
            v.x = f2bf(tile[si * 16 + kb + j0 + 0][cl]);
            v.y = f2bf(tile[si * 16 + kb + j0 + 1][cl]);
            v.z = f2bf(tile[si * 16 + kb + j0 + 2][cl]);
            v.w = f2bf(tile[si * 16 + kb + j0 + 3][cl]);
            *(ushort4*)(wt + ((((size_t)gco * SL) + s) << 9) + l * 8 + j0) = v;
        }
        return;
    }

    // ---- bilinear sampling: 4 vertices per block ----
    {
        int p = (blk - 2336) * 4 + (tid >> 6);   // b*NPTS + n
        int b = p >> 10;
        int n = p & 1023;
        int t = tid & 63;                        // 4 channels each

        float y = vertices[2 * p + 0];
        float x = vertices[2 * p + 1];
        float y0f = floorf(y), x0f = floorf(x);
        float wy1 = y - y0f, wx1 = x - x0f;
        float wy0 = 1.f - wy1, wx0 = 1.f - wx1;
        int y0 = (int)y0f, x0 = (int)x0f;

        float4 acc = make_float4(0.f, 0.f, 0.f, 0.f);
        const float4* fbase = (const float4*)features + (size_t)b * FH * FW * (FC / 4);

#define CORNER(yi, xi, wgt) {                                                  \
        int yy = (yi), xx = (xi);                                              \
        float wv = ((yy >= 0) && (yy < FH) && (xx >= 0) && (xx < FW)) ? (wgt) : 0.f; \
        int yc = yy < 0 ? 0 : (yy > FH - 1 ? FH - 1 : yy);                     \
        int xc = xx < 0 ? 0 : (xx > FW - 1 ? FW - 1 : xx);                     \
        float4 v = fbase[((size_t)yc * FW + xc) * (FC / 4) + t];               \
        acc.x += v.x * wv; acc.y += v.y * wv; acc.z += v.z * wv; acc.w += v.w * wv; }

        CORNER(y0,     x0,     wy0 * wx0);
        CORNER(y0,     x0 + 1, wy0 * wx1);
        CORNER(y0 + 1, x0,     wy1 * wx0);
        CORNER(y0 + 1, x0 + 1, wy1 * wx1);
#undef CORNER

        ushort4 o;
        o.x = f2bf(acc.x); o.y = f2bf(acc.y); o.z = f2bf(acc.z); o.w = f2bf(acc.w);
        *(ushort4*)(XpA + ((size_t)b * PADN + HALO + n) * FC + 4 * t) = o;
    }
}

// ---------------------------------------------------------------------------
// Dilated conv as MFMA GEMM with TAP-SHARED A staging.
// Loop over ci-chunks (64 ci).  Per chunk: stage A[160][64] (128 rows +
// 16-row halo each side, one fetch per row) and compute ALL 3 taps from the
// same LDS tile at row offsets 16+(t-1)*rate.  A L2-traffic drops 3x.
// Tile 128x64 (M x CO), 4 waves (2x2), wave tile 64x32.
// A: 3 x 20 KB LDS buffers, prefetch depth 2 (5 gload_lds/wave/chunk).
// B: direct L2->regs, fragment-ordered, 12 frags/chunk, double reg set.
// Per-wave vmcnt FIFO at chunk entry: [A(c) 5][B(c) 12][A(c+1) 5]
// -> vmcnt(5) retires A(c)+B(c), keeps A(c+1) in flight.  One barrier/chunk.
// Grid 512, XCD decode: the 8 co-blocks of one m-panel share one XCD.
// ---------------------------------------------------------------------------
template <int CIN>
__global__ __launch_bounds__(256, 2) void conv_mfma(
    const ushort_t* __restrict__ Xp,   // [8][1056][CIN] bf16
    const ushort_t* __restrict__ Wf,   // fragment-ordered weights
    const float* __restrict__ bias,    // [512] fp32
    ushort_t* __restrict__ Yp,         // [8][1056][512] bf16 (interior write)
    int rate)
{
    constexpr int NC  = CIN / 64;      // ci-chunks: 4 (FC) or 8 (HID)
    constexpr int SL3 = CIN / 16;      // k-slices per tap
    constexpr int SL  = 3 * SL3;       // k-slices total
    __shared__ short lds[3][10240];    // 3 x A[160][64] = 3 x 20 KB

    const int tid  = threadIdx.x;
    const int wid  = tid >> 6;
    const int lane = tid & 63;
    const int wm   = wid >> 1, wn = wid & 1;

    const int h  = blockIdx.x;               // 0..511
    const int bm = (h & 7) * 8 + (h >> 6);   // 0..63  (XCD h%8 owns 8 m-panels)
    const int bn = (h >> 3) & 7;             // 0..7
    const int batch = bm >> 3;
    const int n0    = (bm & 7) * 128;
    const int co0   = bn * 64;

    // staging base: absolute padded row n0 (= output row n0 - 16 + HALO)
    const short* Xbase = (const short*)Xp + ((size_t)batch * PADN + n0) * CIN;
    const short* Wb = (const short*)Wf
                    + (((size_t)(bn * 2 + wn) * SL) << 9) + lane * 8;

    // ---- A staging: chunk c = rows n0..n0+159 (abs padded), ci [c*64, +64) ----
    // 1280 16B-slots, 5 per lane; slot = it*256 + wid*64 + lane.
    auto stageA = [&](int buf, int c) {
        const short* Ag = Xbase + c * 64;
        short* ldsA = &lds[buf][0];
#pragma unroll
        for (int it = 0; it < 5; ++it) {
            int slot = it * 256 + wid * 64 + lane;
            int row  = slot >> 3;
            int chnk = (slot & 7) ^ (row & 7);    // inverse swizzle on src
            GLOAD16(Ag + (size_t)row * CIN + chnk * 8,
                    ldsA + (size_t)(it * 256 + wid * 64) * 8);
        }
    };
    // ---- B fragments for one chunk: 12 coalesced 16B asm loads into regs ----
    auto loadB = [&](short8* dst, int c) {
#pragma unroll
        for (int t = 0; t < 3; ++t)
#pragma unroll
            for (int ks = 0; ks < 4; ++ks)
                dst[t * 4 + ks] = gread16(Wb + ((size_t)(t * SL3 + c * 4 + ks) << 9));
    };

    // ---- accumulators init with bias ----
    f32x16 acc[2];
    const int rowA0 = wm * 64 + (lane & 31);
    const int coB   = wn * 32 + (lane & 31);
    {
        float bv = bias[co0 + coB];
#pragma unroll
        for (int i = 0; i < 2; ++i)
#pragma unroll
            for (int r = 0; r < 16; ++r) acc[i][r] = bv;
    }

    short8 B0[12], B1[12];
    stageA(0, 0);
    __builtin_amdgcn_sched_barrier(0);
    loadB(B0, 0);
    __builtin_amdgcn_sched_barrier(0);
    stageA(1, 1);
    __builtin_amdgcn_sched_barrier(0);

    int cur = 0;
    auto kstep = [&](int c, short8* Bcur, short8* Bnxt) {
        if (c == NC - 1) asm volatile("s_waitcnt vmcnt(0)" ::: "memory");
        else             asm volatile("s_waitcnt vmcnt(5)" ::: "memory");
        __builtin_amdgcn_s_barrier();
        __builtin_amdgcn_sched_barrier(0);

        if (c + 1 < NC) loadB(Bnxt, c + 1);
        __builtin_amdgcn_sched_barrier(0);        // pin FIFO order: B then A-stage
        if (c + 2 < NC) {
            int nb = cur + 2; if (nb >= 3) nb -= 3;
            stageA(nb, c + 2);
        }
        __builtin_amdgcn_sched_barrier(0);

        const short* As = &lds[cur][0];
        __builtin_amdgcn_s_setprio(1);
#pragma unroll
        for (int t = 0; t < 3; ++t) {
            const int shift = 16 + (t - 1) * rate;
            short8 av[2][4];
#pragma unroll
            for (int ks = 0; ks < 4; ++ks) {
                int ch = ks * 2 + (lane >> 5);
#pragma unroll
                for (int i = 0; i < 2; ++i) {
                    int rr = rowA0 + i * 32 + shift;
                    av[i][ks] = *(const short8*)(As + rr * 64 + ((ch ^ (rr & 7)) << 3));
                }
            }
#pragma unroll
            for (int ks = 0; ks < 4; ++ks)
#pragma unroll
                for (int i = 0; i < 2; ++i)
                    acc[i] = __builtin_amdgcn_mfma_f32_32x32x16_bf16(
                        av[i][ks], Bcur[t * 4 + ks], acc[i], 0, 0, 0);
        }
        __builtin_amdgcn_s_setprio(0);
        cur += 1; if (cur >= 3) cur -= 3;
    };

    for (int c = 0; c < NC; c += 2) {
        kstep(c,     B0, B1);
        kstep(c + 1, B1, B0);
    }

    // ---- epilogue: ReLU + bf16 store into padded interior ----
    ushort_t* Yb = Yp + ((size_t)batch * PADN + HALO + n0) * HID + co0;
#pragma unroll
    for (int i = 0; i < 2; ++i) {
#pragma unroll
        for (int r = 0; r < 16; ++r) {
            int rrow = wm * 64 + i * 32 + (r & 3) + 8 * (r >> 2) + 4 * (lane >> 5);
            float v = acc[i][r];
            v = v > 0.f ? v : 0.f;
            Yb[(size_t)rrow * HID + coB] = f2bf(v);
        }
    }
}

// ---------------------------------------------------------------------------
// Offset head: out[p,:] = vertices[p,:] + h[p,:] @ w_off  (bf16 h, fp32 w)
// ---------------------------------------------------------------------------
__global__ __launch_bounds__(64) void head_kernel(
    const ushort_t* __restrict__ h, const float* __restrict__ w_off,
    const float* __restrict__ vertices, float* __restrict__ out)
{
    int p = blockIdx.x;
    int b = p >> 10, n = p & 1023;
    int t = threadIdx.x;
    const ushort_t* hr = h + ((size_t)b * PADN + HALO + n) * HID + t * 8;

    uint4 raw = *(const uint4*)hr;
    ushort_t hv[8];
    hv[0] = raw.x & 0xffff; hv[1] = raw.x >> 16;
    hv[2] = raw.y & 0xffff; hv[3] = raw.y >> 16;
    hv[4] = raw.z & 0xffff; hv[5] = raw.z >> 16;
    hv[6] = raw.w & 0xffff; hv[7] = raw.w >> 16;

    float s0 = 0.f, s1 = 0.f;
#pragma unroll
    for (int k = 0; k < 8; ++k) {
        float x = bf2f(hv[k]);
        s0 += x * w_off[(t * 8 + k) * 2 + 0];
        s1 += x * w_off[(t * 8 + k) * 2 + 1];
    }
#pragma unroll
    for (int off = 32; off >= 1; off >>= 1) {
        s0 += __shfl_down(s0, off);
        s1 += __shfl_down(s1, off);
    }
    if (t == 0) {
        out[2 * p + 0] = vertices[2 * p + 0] + s0;
        out[2 * p + 1] = vertices[2 * p + 1] + s1;
    }
}

// ---------------------------------------------------------------------------
extern "C" void kernel_launch(void* const* d_in, const int* in_sizes, int n_in,
                              void* d_out, int out_size, void* d_ws, size_t ws_size,
                              hipStream_t stream)
{
    (void)in_sizes; (void)n_in; (void)out_size; (void)ws_size;

    const float* vertices = (const float*)d_in[0];
    const float* features = (const float*)d_in[1];
    const float* w[6]  = {(const float*)d_in[2], (const float*)d_in[4],
                          (const float*)d_in[6], (const float*)d_in[8],
                          (const float*)d_in[10], (const float*)d_in[12]};
    const float* bb[6] = {(const float*)d_in[3], (const float*)d_in[5],
                          (const float*)d_in[7], (const float*)d_in[9],
                          (const float*)d_in[11], (const float*)d_in[13]};
    const float* w_off = (const float*)d_in[14];
    float* out = (float*)d_out;

    // ---- workspace layout ----
    char* p = (char*)d_ws;
    ushort_t* wt[6];
    wt[0] = (ushort_t*)p; p += (size_t)HID * (3 * FC) * 2;          // 768 KB
    for (int i = 1; i < 6; ++i) { wt[i] = (ushort_t*)p; p += (size_t)HID * (3 * HID) * 2; }
    ushort_t* XpA = (ushort_t*)p; p += (size_t)BATCH * PADN * FC  * 2;
    ushort_t* XpB = (ushort_t*)p; p += (size_t)BATCH * PADN * HID * 2;
    ushort_t* XpC = (ushort_t*)p;

    // ---- fused prep: halos + fragment-ordered weights + sampling ----
    prep_kernel<<<4384, 256, 0, stream>>>(
        vertices, features, w[0], w[1], w[2], w[3], w[4], w[5],
        wt[0], wt[1], wt[2], wt[3], wt[4], wt[5], XpA, XpB, XpC);

    // ---- conv stack (A -> B -> C -> B -> C -> B -> C) ----
    static const int rates[6] = {1, 3, 9, 9, 3, 1};
    conv_mfma<FC><<<512, 256, 0, stream>>>(XpA, wt[0], bb[0], XpB, rates[0]);
    ushort_t* src = XpB;
    ushort_t* dst = XpC;
    for (int i = 1; i < 6; ++i) {
        conv_mfma<HID><<<512, 256, 0, stream>>>(src, wt[i], bb[i], dst, rates[i]);
        ushort_t* tmp = src; src = dst; dst = tmp;
    }

    // ---- head ----
    head_kernel<<<BATCH * NPTS, 64, 0, stream>>>(src, w_off, vertices, out);
}

// Round 10
// 121.294 us; speedup vs baseline: 1.2770x; 1.0049x over previous
//
#include <hip/hip_runtime.h>

#define BATCH 8
#define NPTS  1024
#define FH    256
#define FW    256
#define FC    256
#define HID   512
#define PADN  1056          // 16-row halo each side (rate <= 9)
#define HALO  16

typedef __attribute__((ext_vector_type(8))) short short8;
typedef __attribute__((ext_vector_type(16))) float f32x16;
typedef unsigned short ushort_t;
typedef unsigned int uint_t;

__device__ __forceinline__ ushort_t f2bf(float f) {
    uint_t u = __builtin_bit_cast(uint_t, f);
    u += 0x7fffu + ((u >> 16) & 1u);          // round-to-nearest-even
    return (ushort_t)(u >> 16);
}
__device__ __forceinline__ float bf2f(ushort_t s) {
    uint_t u = ((uint_t)s) << 16;
    return __builtin_bit_cast(float, u);
}

#define GLOAD16(g, l)                                                     \
    __builtin_amdgcn_global_load_lds(                                     \
        (const __attribute__((address_space(1))) void*)(g),               \
        (__attribute__((address_space(3))) void*)(l), 16, 0, 0)

// Opaque global->VGPR 16B load: keeps the per-wave vmcnt FIFO count exact.
__device__ __forceinline__ short8 gread16(const short* p) {
    short8 r;
    asm volatile("global_load_dwordx4 %0, %1, off" : "=v"(r) : "v"(p));
    return r;
}

// ---------------------------------------------------------------------------
// Fused prep kernel: [0,1280) halo zeroing, [1280,2336) weight transform into
// MFMA-fragment order, [2336,4384) bilinear sampling (4 vertices per block).
//
// Fragment-ordered weights: block (gco, s) of 512 shorts (1 KB), gco = co/32,
// s = k/16 (k = tap*CIN+ci).  Element at short-offset l*8 + j holds
// w[k = s*16 + (l>>5)*8 + j][co = gco*32 + (l&31)]  -- lane l's 16-byte B
// fragment for mfma_f32_32x32x16_bf16.
// ---------------------------------------------------------------------------
__global__ __launch_bounds__(256) void prep_kernel(
    const float* __restrict__ vertices, const float* __restrict__ features,
    const float* __restrict__ w0, const float* __restrict__ w1,
    const float* __restrict__ w2, const float* __restrict__ w3,
    const float* __restrict__ w4, const float* __restrict__ w5,
    ushort_t* __restrict__ wt0, ushort_t* __restrict__ wt1,
    ushort_t* __restrict__ wt2, ushort_t* __restrict__ wt3,
    ushort_t* __restrict__ wt4, ushort_t* __restrict__ wt5,
    ushort_t* __restrict__ XpA, ushort_t* __restrict__ XpB,
    ushort_t* __restrict__ XpC)
{
    __shared__ float tile[64][65];
    const int blk = blockIdx.x;
    const int tid = threadIdx.x;

    if (blk < 1280) {
        // ---- halo zeroing ----
        int i = blk * 256 + tid;
        if (i < 65536) {                   // A halos: 8 * 2 strips * 16*256
            int b = i >> 13, rem = i & 8191;
            int strip = rem >> 12, off = rem & 4095;
            XpA[(size_t)b * (PADN * FC) + (strip ? (PADN - HALO) * FC : 0) + off] = 0;
        }
        int jB = i - 65536;                // B,C halos: 8 * 2 strips * 16*512
        if (jB >= 0 && jB < 262144) {
            ushort_t* T = (jB < 131072) ? XpB : XpC;
            int j = jB & 131071;
            int b = j >> 14, rem = j & 16383;
            int strip = rem >> 13, off = rem & 8191;
            T[(size_t)b * (PADN * HID) + (strip ? (PADN - HALO) * HID : 0) + off] = 0;
        }
        return;
    }

    if (blk < 2336) {
        // ---- weight transform: w [3][CIN][512] fp32 -> fragment-ordered bf16 ----
        int j = blk - 1280;
        const float* w; ushort_t* wt; int CIN, kk0, co0;
        if (j < 96) {
            w = w0; wt = wt0; CIN = FC;
            kk0 = (j % 12) * 64; co0 = (j / 12) * 64;
        } else {
            int j2 = j - 96;
            int layer = j2 / 192, jj = j2 % 192;
            const float* ws[5]  = {w1, w2, w3, w4, w5};
            ushort_t*   wts[5]  = {wt1, wt2, wt3, wt4, wt5};
            w = ws[layer]; wt = wts[layer]; CIN = HID;
            kk0 = (jj % 24) * 64; co0 = (jj / 24) * 64;
        }
        int tap = kk0 / CIN, ci0 = kk0 - tap * CIN;
        int SL  = (3 * CIN) >> 4;          // k-slices total
        // stage tile[k_local][co_local]
#pragma unroll 4
        for (int it = 0; it < 16; ++it) {
            int r = it * 4 + (tid >> 6);
            tile[r][tid & 63] = w[((size_t)tap * CIN + ci0 + r) * HID + co0 + (tid & 63)];
        }
        __syncthreads();
        // emit fragment blocks
        int gl  = tid >> 7;                // 0..1: co-group within 64-co panel
        int r2  = tid & 127;
        int l   = r2 >> 1;                 // lane 0..63
        int j0  = (r2 & 1) * 4;
        int gco = (co0 >> 5) + gl;
        int kb  = ((l >> 5) << 3);         // k base within slice from lane
        int cl  = gl * 32 + (l & 31);      // co_local
#pragma unroll
        for (int si = 0; si < 4; ++si) {
            int s = (kk0 >> 4) + si;
            ushort4 v;
            v.x = f2bf(tile[si * 16 + kb + j0 + 0][cl]);
            v.y = f2bf(tile[si * 16 + kb + j0 + 1][cl]);
            v.z = f2bf(tile[si * 16 + kb + j0 + 2][cl]);
            v.w = f2bf(tile[si * 16 + kb + j0 + 3][cl]);
            *(ushort4*)(wt + ((((size_t)gco * SL) + s) << 9) + l * 8 + j0) = v;
        }
        return;
    }

    // ---- bilinear sampling: 4 vertices per block ----
    {
        int p = (blk - 2336) * 4 + (tid >> 6);   // b*NPTS + n
        int b = p >> 10;
        int n = p & 1023;
        int t = tid & 63;                        // 4 channels each

        float y = vertices[2 * p + 0];
        float x = vertices[2 * p + 1];
        float y0f = floorf(y), x0f = floorf(x);
        float wy1 = y - y0f, wx1 = x - x0f;
        float wy0 = 1.f - wy1, wx0 = 1.f - wx1;
        int y0 = (int)y0f, x0 = (int)x0f;

        float4 acc = make_float4(0.f, 0.f, 0.f, 0.f);
        const float4* fbase = (const float4*)features + (size_t)b * FH * FW * (FC / 4);

#define CORNER(yi, xi, wgt) {                                                  \
        int yy = (yi), xx = (xi);                                              \
        float wv = ((yy >= 0) && (yy < FH) && (xx >= 0) && (xx < FW)) ? (wgt) : 0.f; \
        int yc = yy < 0 ? 0 : (yy > FH - 1 ? FH - 1 : yy);                     \
        int xc = xx < 0 ? 0 : (xx > FW - 1 ? FW - 1 : xx);                     \
        float4 v = fbase[((size_t)yc * FW + xc) * (FC / 4) + t];               \
        acc.x += v.x * wv; acc.y += v.y * wv; acc.z += v.z * wv; acc.w += v.w * wv; }

        CORNER(y0,     x0,     wy0 * wx0);
        CORNER(y0,     x0 + 1, wy0 * wx1);
        CORNER(y0 + 1, x0,     wy1 * wx0);
        CORNER(y0 + 1, x0 + 1, wy1 * wx1);
#undef CORNER

        ushort4 o;
        o.x = f2bf(acc.x); o.y = f2bf(acc.y); o.z = f2bf(acc.z); o.w = f2bf(acc.w);
        *(ushort4*)(XpA + ((size_t)b * PADN + HALO + n) * FC + 4 * t) = o;
    }
}

// ---------------------------------------------------------------------------
// Dilated conv as MFMA GEMM, tap-shared A staging, K-SPLIT 8-wave version.
// Tile 128x64 (M x CO), 512 threads = 8 waves as (wm 2) x (wn 2) x (wk 2):
// wave tile 64x32; wk-halves split the 4 k-slices per tap (2 each) and
// accumulate partials, added via LDS in the epilogue.  Identical per-CU
// traffic (A 84 MB, B dup-2 196 MB, LDS 1536 reads) to the R9 4-wave kernel;
// ONLY occupancy changes: 16 waves/CU = 4 waves/SIMD (was 2).
// A: 2 x 20 KB LDS double-buffer, 1-ahead prefetch.  B: frag-ordered, direct
// L2->regs (6 frags/wave/chunk, double reg set).
// Per-wave vmcnt FIFO (stage k in {2,3} by wave, B 6):
//   before MFMA: [B(c) 6][stage(c+1) k] -> vmcnt(2) retires B(c);
//   before barrier: [stage(c+1) k][B(c+1) 6] -> vmcnt(6) retires stage.
// Grid 512, XCD decode: the 8 co-blocks of one m-panel share one XCD.
// ---------------------------------------------------------------------------
template <int CIN>
__global__ __launch_bounds__(512, 4) void conv_mfma(
    const ushort_t* __restrict__ Xp,   // [8][1056][CIN] bf16
    const ushort_t* __restrict__ Wf,   // fragment-ordered weights
    const float* __restrict__ bias,    // [512] fp32
    ushort_t* __restrict__ Yp,         // [8][1056][512] bf16 (interior write)
    int rate)
{
    constexpr int NC  = CIN / 64;      // ci-chunks: 4 (FC) or 8 (HID)
    constexpr int SL3 = CIN / 16;      // k-slices per tap
    constexpr int SL  = 3 * SL3;       // k-slices total
    __shared__ short lds[2][10240];    // 2 x A[160][64] = 40 KB (epilogue reuse)

    const int tid  = threadIdx.x;      // 0..511
    const int wid  = tid >> 6;         // 0..7
    const int lane = tid & 63;
    const int wm   = wid >> 2;         // 0..1  (M half)
    const int wn   = (wid >> 1) & 1;   // 0..1  (CO half)
    const int wk   = wid & 1;          // 0..1  (k-slice half)

    const int h  = blockIdx.x;               // 0..511
    const int bm = (h & 7) * 8 + (h >> 6);   // 0..63  (XCD h%8 owns 8 m-panels)
    const int bn = (h >> 3) & 7;             // 0..7
    const int batch = bm >> 3;
    const int n0    = (bm & 7) * 128;
    const int co0   = bn * 64;

    // staging base: absolute padded row n0 (= output row n0 - 16 + HALO)
    const short* Xbase = (const short*)Xp + ((size_t)batch * PADN + n0) * CIN;
    const short* Wb = (const short*)Wf
                    + (((size_t)(bn * 2 + wn) * SL) << 9) + lane * 8;

    // ---- A staging: chunk c = rows n0..n0+159 (abs padded), ci [c*64,+64) ----
    // 1280 16B-slots over 8 waves: it=0,1 all waves, it=2 waves 0-3 only
    // (wave-uniform branch; per-wave gload count k = 3 or 2).
    auto stageA = [&](int buf, int c) {
        const short* Ag = Xbase + c * 64;
        short* ldsA = &lds[buf][0];
#pragma unroll
        for (int it = 0; it < 2; ++it) {
            int slot = it * 512 + wid * 64 + lane;
            int row  = slot >> 3;
            int chnk = (slot & 7) ^ (row & 7);    // inverse swizzle on src
            GLOAD16(Ag + (size_t)row * CIN + chnk * 8,
                    ldsA + (size_t)(it * 512 + wid * 64) * 8);
        }
        if (wid < 4) {
            int slot = 1024 + wid * 64 + lane;
            int row  = slot >> 3;
            int chnk = (slot & 7) ^ (row & 7);
            GLOAD16(Ag + (size_t)row * CIN + chnk * 8,
                    ldsA + (size_t)(1024 + wid * 64) * 8);
        }
    };
    // ---- B fragments: this wave's 6 (3 taps x 2 k-slices) per chunk ----
    auto loadB = [&](short8* dst, int c) {
#pragma unroll
        for (int t = 0; t < 3; ++t)
#pragma unroll
            for (int ksh = 0; ksh < 2; ++ksh)
                dst[t * 2 + ksh] =
                    gread16(Wb + ((size_t)(t * SL3 + c * 4 + wk * 2 + ksh) << 9));
    };

    // ---- accumulators: bias only on wk=0 (partials are summed later) ----
    f32x16 acc[2];
    const int rowA0 = wm * 64 + (lane & 31);
    const int coB   = wn * 32 + (lane & 31);
    {
        float bv = (wk == 0) ? bias[co0 + coB] : 0.f;
#pragma unroll
        for (int i = 0; i < 2; ++i)
#pragma unroll
            for (int r = 0; r < 16; ++r) acc[i][r] = bv;
    }

    short8 B0[6], B1[6];
    stageA(0, 0);
    __builtin_amdgcn_sched_barrier(0);
    loadB(B0, 0);
    __builtin_amdgcn_sched_barrier(0);
    asm volatile("s_waitcnt vmcnt(6)" ::: "memory");   // A(0) landed, B0 in flight
    __builtin_amdgcn_s_barrier();
    __builtin_amdgcn_sched_barrier(0);

    int cur = 0;
    auto kstep = [&](int c, short8* Bcur, short8* Bnxt) {
        if (c + 1 < NC) stageA(cur ^ 1, c + 1);
        __builtin_amdgcn_sched_barrier(0);

        // retire B(c); leave stage(c+1) in flight
        if (c + 1 < NC) asm volatile("s_waitcnt vmcnt(2)" ::: "memory");
        else            asm volatile("s_waitcnt vmcnt(0)" ::: "memory");
        __builtin_amdgcn_sched_barrier(0);        // rule 18: no MFMA hoist

        const short* As = &lds[cur][0];
        __builtin_amdgcn_s_setprio(1);
#pragma unroll
        for (int t = 0; t < 3; ++t) {
            const int shift = 16 + (t - 1) * rate;
#pragma unroll
            for (int ksh = 0; ksh < 2; ++ksh) {
                int ch = (wk * 2 + ksh) * 2 + (lane >> 5);
#pragma unroll
                for (int i = 0; i < 2; ++i) {
                    int rr = rowA0 + i * 32 + shift;
                    short8 av = *(const short8*)(As + rr * 64 + ((ch ^ (rr & 7)) << 3));
                    acc[i] = __builtin_amdgcn_mfma_f32_32x32x16_bf16(
                        av, Bcur[t * 2 + ksh], acc[i], 0, 0, 0);
                }
            }
        }
        __builtin_amdgcn_s_setprio(0);
        __builtin_amdgcn_sched_barrier(0);

        if (c + 1 < NC) {
            loadB(Bnxt, c + 1);
            __builtin_amdgcn_sched_barrier(0);
            asm volatile("s_waitcnt vmcnt(6)" ::: "memory");  // stage(c+1) retired
        }
        __builtin_amdgcn_s_barrier();
        cur ^= 1;
    };

    for (int c = 0; c < NC; c += 2) {
        kstep(c,     B0, B1);
        kstep(c + 1, B1, B0);
    }

    // ---- epilogue: wk=1 partials -> LDS; wk=0 adds, ReLU, bf16 store ----
    float* pf = (float*)&lds[0][0];               // 4 pairs x 8 KB = 32 KB
    const int pair = wm * 2 + wn;
    if (wk == 1) {
#pragma unroll
        for (int i = 0; i < 2; ++i)
#pragma unroll
            for (int r = 0; r < 16; ++r)
                pf[pair * 2048 + (i * 16 + r) * 64 + lane] = acc[i][r];
    }
    __syncthreads();
    if (wk == 0) {
        ushort_t* Yb = Yp + ((size_t)batch * PADN + HALO + n0) * HID + co0;
#pragma unroll
        for (int i = 0; i < 2; ++i) {
#pragma unroll
            for (int r = 0; r < 16; ++r) {
                int rrow = wm * 64 + i * 32 + (r & 3) + 8 * (r >> 2) + 4 * (lane >> 5);
                float v = acc[i][r] + pf[pair * 2048 + (i * 16 + r) * 64 + lane];
                v = v > 0.f ? v : 0.f;
                Yb[(size_t)rrow * HID + coB] = f2bf(v);
            }
        }
    }
}

// ---------------------------------------------------------------------------
// Offset head: out[p,:] = vertices[p,:] + h[p,:] @ w_off  (bf16 h, fp32 w)
// ---------------------------------------------------------------------------
__global__ __launch_bounds__(64) void head_kernel(
    const ushort_t* __restrict__ h, const float* __restrict__ w_off,
    const float* __restrict__ vertices, float* __restrict__ out)
{
    int p = blockIdx.x;
    int b = p >> 10, n = p & 1023;
    int t = threadIdx.x;
    const ushort_t* hr = h + ((size_t)b * PADN + HALO + n) * HID + t * 8;

    uint4 raw = *(const uint4*)hr;
    ushort_t hv[8];
    hv[0] = raw.x & 0xffff; hv[1] = raw.x >> 16;
    hv[2] = raw.y & 0xffff; hv[3] = raw.y >> 16;
    hv[4] = raw.z & 0xffff; hv[5] = raw.z >> 16;
    hv[6] = raw.w & 0xffff; hv[7] = raw.w >> 16;

    float s0 = 0.f, s1 = 0.f;
#pragma unroll
    for (int k = 0; k < 8; ++k) {
        float x = bf2f(hv[k]);
        s0 += x * w_off[(t * 8 + k) * 2 + 0];
        s1 += x * w_off[(t * 8 + k) * 2 + 1];
    }
#pragma unroll
    for (int off = 32; off >= 1; off >>= 1) {
        s0 += __shfl_down(s0, off);
        s1 += __shfl_down(s1, off);
    }
    if (t == 0) {
        out[2 * p + 0] = vertices[2 * p + 0] + s0;
        out[2 * p + 1] = vertices[2 * p + 1] + s1;
    }
}

// ---------------------------------------------------------------------------
extern "C" void kernel_launch(void* const* d_in, const int* in_sizes, int n_in,
                              void* d_out, int out_size, void* d_ws, size_t ws_size,
                              hipStream_t stream)
{
    (void)in_sizes; (void)n_in; (void)out_size; (void)ws_size;

    const float* vertices = (const float*)d_in[0];
    const float* features = (const float*)d_in[1];
    const float* w[6]  = {(const float*)d_in[2], (const float*)d_in[4],
                          (const float*)d_in[6], (const float*)d_in[8],
                          (const float*)d_in[10], (const float*)d_in[12]};
    const float* bb[6] = {(const float*)d_in[3], (const float*)d_in[5],
                          (const float*)d_in[7], (const float*)d_in[9],
                          (const float*)d_in[11], (const float*)d_in[13]};
    const float* w_off = (const float*)d_in[14];
    float* out = (float*)d_out;

    // ---- workspace layout ----
    char* p = (char*)d_ws;
    ushort_t* wt[6];
    wt[0] = (ushort_t*)p; p += (size_t)HID * (3 * FC) * 2;          // 768 KB
    for (int i = 1; i < 6; ++i) { wt[i] = (ushort_t*)p; p += (size_t)HID * (3 * HID) * 2; }
    ushort_t* XpA = (ushort_t*)p; p += (size_t)BATCH * PADN * FC  * 2;
    ushort_t* XpB = (ushort_t*)p; p += (size_t)BATCH * PADN * HID * 2;
    ushort_t* XpC = (ushort_t*)p;

    // ---- fused prep: halos + fragment-ordered weights + sampling ----
    prep_kernel<<<4384, 256, 0, stream>>>(
        vertices, features, w[0], w[1], w[2], w[3], w[4], w[5],
        wt[0], wt[1], wt[2], wt[3], wt[4], wt[5], XpA, XpB, XpC);

    // ---- conv stack (A -> B -> C -> B -> C -> B -> C) ----
    static const int rates[6] = {1, 3, 9, 9, 3, 1};
    conv_mfma<FC><<<512, 512, 0, stream>>>(XpA, wt[0], bb[0], XpB, rates[0]);
    ushort_t* src = XpB;
    ushort_t* dst = XpC;
    for (int i = 1; i < 6; ++i) {
        conv_mfma<HID><<<512, 512, 0, stream>>>(src, wt[i], bb[i], dst, rates[i]);
        ushort_t* tmp = src; src = dst; dst = tmp;
    }

    // ---- head ----
    head_kernel<<<BATCH * NPTS, 64, 0, stream>>>(src, w_off, vertices, out);
}

// Round 11
// 117.089 us; speedup vs baseline: 1.3229x; 1.0359x over previous
//
#include <hip/hip_runtime.h>

#define BATCH 8
#define NPTS  1024
#define FH    256
#define FW    256
#define FC    256
#define HID   512
#define PADN  1056          // 16-row halo each side (rate <= 9)
#define HALO  16

typedef __attribute__((ext_vector_type(8))) short short8;
typedef __attribute__((ext_vector_type(16))) float f32x16;
typedef unsigned short ushort_t;
typedef unsigned int uint_t;

__device__ __forceinline__ ushort_t f2bf(float f) {
    uint_t u = __builtin_bit_cast(uint_t, f);
    u += 0x7fffu + ((u >> 16) & 1u);          // round-to-nearest-even
    return (ushort_t)(u >> 16);
}
__device__ __forceinline__ float bf2f(ushort_t s) {
    uint_t u = ((uint_t)s) << 16;
    return __builtin_bit_cast(float, u);
}

#define GLOAD16(g, l)                                                     \
    __builtin_amdgcn_global_load_lds(                                     \
        (const __attribute__((address_space(1))) void*)(g),               \
        (__attribute__((address_space(3))) void*)(l), 16, 0, 0)

// Opaque global->VGPR 16B load: keeps the per-wave vmcnt FIFO count exact.
__device__ __forceinline__ short8 gread16(const short* p) {
    short8 r;
    asm volatile("global_load_dwordx4 %0, %1, off" : "=v"(r) : "v"(p));
    return r;
}

// ---------------------------------------------------------------------------
// Fused prep kernel: [0,1280) halo zeroing, [1280,2336) weight transform into
// MFMA-fragment order, [2336,4384) bilinear sampling (4 vertices per block).
//
// Fragment-ordered weights: block (gco, s) of 512 shorts (1 KB), gco = co/32,
// s = k/16 (k = tap*CIN+ci).  Element at short-offset l*8 + j holds
// w[k = s*16 + (l>>5)*8 + j][co = gco*32 + (l&31)]  -- lane l's 16-byte B
// fragment for mfma_f32_32x32x16_bf16.
// ---------------------------------------------------------------------------
__global__ __launch_bounds__(256) void prep_kernel(
    const float* __restrict__ vertices, const float* __restrict__ features,
    const float* __restrict__ w0, const float* __restrict__ w1,
    const float* __restrict__ w2, const float* __restrict__ w3,
    const float* __restrict__ w4, const float* __restrict__ w5,
    ushort_t* __restrict__ wt0, ushort_t* __restrict__ wt1,
    ushort_t* __restrict__ wt2, ushort_t* __restrict__ wt3,
    ushort_t* __restrict__ wt4, ushort_t* __restrict__ wt5,
    ushort_t* __restrict__ XpA, ushort_t* __restrict__ XpB,
    ushort_t* __restrict__ XpC)
{
    __shared__ float tile[64][65];
    const int blk = blockIdx.x;
    const int tid = threadIdx.x;

    if (blk < 1280) {
        // ---- halo zeroing ----
        int i = blk * 256 + tid;
        if (i < 65536) {                   // A halos: 8 * 2 strips * 16*256
            int b = i >> 13, rem = i & 8191;
            int strip = rem >> 12, off = rem & 4095;
            XpA[(size_t)b * (PADN * FC) + (strip ? (PADN - HALO) * FC : 0) + off] = 0;
        }
        int jB = i - 65536;                // B,C halos: 8 * 2 strips * 16*512
        if (jB >= 0 && jB < 262144) {
            ushort_t* T = (jB < 131072) ? XpB : XpC;
            int j = jB & 131071;
            int b = j >> 14, rem = j & 16383;
            int strip = rem >> 13, off = rem & 8191;
            T[(size_t)b * (PADN * HID) + (strip ? (PADN - HALO) * HID : 0) + off] = 0;
        }
        return;
    }

    if (blk < 2336) {
        // ---- weight transform: w [3][CIN][512] fp32 -> fragment-ordered bf16 ----
        int j = blk - 1280;
        const float* w; ushort_t* wt; int CIN, kk0, co0;
        if (j < 96) {
            w = w0; wt = wt0; CIN = FC;
            kk0 = (j % 12) * 64; co0 = (j / 12) * 64;
        } else {
            int j2 = j - 96;
            int layer = j2 / 192, jj = j2 % 192;
            const float* ws[5]  = {w1, w2, w3, w4, w5};
            ushort_t*   wts[5]  = {wt1, wt2, wt3, wt4, wt5};
            w = ws[layer]; wt = wts[layer]; CIN = HID;
            kk0 = (jj % 24) * 64; co0 = (jj / 24) * 64;
        }
        int tap = kk0 / CIN, ci0 = kk0 - tap * CIN;
        int SL  = (3 * CIN) >> 4;          // k-slices total
        // stage tile[k_local][co_local]
#pragma unroll 4
        for (int it = 0; it < 16; ++it) {
            int r = it * 4 + (tid >> 6);
            tile[r][tid & 63] = w[((size_t)tap * CIN + ci0 + r) * HID + co0 + (tid & 63)];
        }
        __syncthreads();
        // emit fragment blocks
        int gl  = tid >> 7;                // 0..1: co-group within 64-co panel
        int r2  = tid & 127;
        int l   = r2 >> 1;                 // lane 0..63
        int j0  = (r2 & 1) * 4;
        int gco = (co0 >> 5) + gl;
        int kb  = ((l >> 5) << 3);         // k base within slice from lane
        int cl  = gl * 32 + (l & 31);      // co_local
#pragma unroll
        for (int si = 0; si < 4; ++si) {
            int s = (kk0 >> 4) + si;
            ushort4 v;
            v.x = f2bf(tile[si * 16 + kb + j0 + 0][cl]);
            v.y = f2bf(tile[si * 16 + kb + j0 + 1][cl]);
            v.z = f2bf(tile[si * 16 + kb + j0 + 2][cl]);
            v.w = f2bf(tile[si * 16 + kb + j0 + 3][cl]);
            *(ushort4*)(wt + ((((size_t)gco * SL) + s) << 9) + l * 8 + j0) = v;
        }
        return;
    }

    // ---- bilinear sampling: 4 vertices per block ----
    {
        int p = (blk - 2336) * 4 + (tid >> 6);   // b*NPTS + n
        int b = p >> 10;
        int n = p & 1023;
        int t = tid & 63;                        // 4 channels each

        float y = vertices[2 * p + 0];
        float x = vertices[2 * p + 1];
        float y0f = floorf(y), x0f = floorf(x);
        float wy1 = y - y0f, wx1 = x - x0f;
        float wy0 = 1.f - wy1, wx0 = 1.f - wx1;
        int y0 = (int)y0f, x0 = (int)x0f;

        float4 acc = make_float4(0.f, 0.f, 0.f, 0.f);
        const float4* fbase = (const float4*)features + (size_t)b * FH * FW * (FC / 4);

#define CORNER(yi, xi, wgt) {                                                  \
        int yy = (yi), xx = (xi);                                              \
        float wv = ((yy >= 0) && (yy < FH) && (xx >= 0) && (xx < FW)) ? (wgt) : 0.f; \
        int yc = yy < 0 ? 0 : (yy > FH - 1 ? FH - 1 : yy);                     \
        int xc = xx < 0 ? 0 : (xx > FW - 1 ? FW - 1 : xx);                     \
        float4 v = fbase[((size_t)yc * FW + xc) * (FC / 4) + t];               \
        acc.x += v.x * wv; acc.y += v.y * wv; acc.z += v.z * wv; acc.w += v.w * wv; }

        CORNER(y0,     x0,     wy0 * wx0);
        CORNER(y0,     x0 + 1, wy0 * wx1);
        CORNER(y0 + 1, x0,     wy1 * wx0);
        CORNER(y0 + 1, x0 + 1, wy1 * wx1);
#undef CORNER

        ushort4 o;
        o.x = f2bf(acc.x); o.y = f2bf(acc.y); o.z = f2bf(acc.z); o.w = f2bf(acc.w);
        *(ushort4*)(XpA + ((size_t)b * PADN + HALO + n) * FC + 4 * t) = o;
    }
}

// ---------------------------------------------------------------------------
// Dilated conv as MFMA GEMM, TALL tile 256x64 (M x CO) to halve B re-reads.
// 512 threads = 8 waves as (wm 2) x (wn 2) x (wk 2); wave tile 128x32
// (4 x 32x32 MFMA), wk-halves split k-slices, partials summed via LDS.
// Per-layer L2 traffic: A 75 MB + B 98 MB + Y 8 MB  (was 84+196+8).
// A: [288][64] tap-shared chunk tiles (16-row halos), 2 x 36 KB double-buffer,
//    1-ahead prefetch, 4-5 gload_lds per wave per chunk.
// B: fragment-ordered, direct L2->regs, 6 frags/wave/chunk, double reg set.
// Per-wave vmcnt FIFO (stage k in {4,5}, B 6):
//   top of chunk: [B(c) 6] -> issue stage(c+1) -> vmcnt(4) retires B(c);
//   after loadB(c+1): [stage(c+1) k][B(c+1) 6] -> vmcnt(6) retires stage.
// Grid 256 = 1 block/CU; XCD decode: 4 m-panels x 8 bn per XCD (~2.7 MB L2).
// ---------------------------------------------------------------------------
template <int CIN>
__global__ __launch_bounds__(512, 2) void conv_mfma(
    const ushort_t* __restrict__ Xp,   // [8][1056][CIN] bf16
    const ushort_t* __restrict__ Wf,   // fragment-ordered weights
    const float* __restrict__ bias,    // [512] fp32
    ushort_t* __restrict__ Yp,         // [8][1056][512] bf16 (interior write)
    int rate)
{
    constexpr int NC  = CIN / 64;      // ci-chunks: 4 (FC) or 8 (HID)
    constexpr int SL3 = CIN / 16;      // k-slices per tap
    constexpr int SL  = 3 * SL3;       // k-slices total
    __shared__ short lds[2][18432];    // 2 x A[288][64] = 72 KB

    const int tid  = threadIdx.x;      // 0..511
    const int wid  = tid >> 6;         // 0..7
    const int lane = tid & 63;
    const int wm   = wid >> 2;         // 0..1  (M half: 128 rows)
    const int wn   = (wid >> 1) & 1;   // 0..1  (CO half: 32 co)
    const int wk   = wid & 1;          // 0..1  (k-slice half)

    const int h  = blockIdx.x;               // 0..255
    const int bm = (h & 7) * 4 + (h >> 6);   // 0..31  (XCD h&7 owns 4 m-panels)
    const int bn = (h >> 3) & 7;             // 0..7
    const int batch = bm >> 2;
    const int n0    = (bm & 3) * 256;
    const int co0   = bn * 64;

    // staging base: absolute padded row n0 (= output row n0 - 16 + HALO)
    const short* Xbase = (const short*)Xp + ((size_t)batch * PADN + n0) * CIN;
    const short* Wb = (const short*)Wf
                    + (((size_t)(bn * 2 + wn) * SL) << 9) + lane * 8;

    // ---- A staging: chunk c = padded rows n0..n0+287, ci [c*64, +64) ----
    // 2304 16B-slots: it 0..3 all waves, extra 256 slots on waves 0-3
    // (wave-uniform branch; per-wave gload count k = 5 or 4).
    auto stageA = [&](int buf, int c) {
        const short* Ag = Xbase + c * 64;
        short* ldsA = &lds[buf][0];
#pragma unroll
        for (int it = 0; it < 4; ++it) {
            int slot = it * 512 + wid * 64 + lane;
            int row  = slot >> 3;
            int chnk = (slot & 7) ^ (row & 7);    // inverse swizzle on src
            GLOAD16(Ag + (size_t)row * CIN + chnk * 8,
                    ldsA + (size_t)(it * 512 + wid * 64) * 8);
        }
        if (wid < 4) {
            int slot = 2048 + wid * 64 + lane;
            int row  = slot >> 3;
            int chnk = (slot & 7) ^ (row & 7);
            GLOAD16(Ag + (size_t)row * CIN + chnk * 8,
                    ldsA + (size_t)(2048 + wid * 64) * 8);
        }
    };
    // ---- B fragments: this wave's 6 (3 taps x 2 k-slices) per chunk ----
    auto loadB = [&](short8* dst, int c) {
#pragma unroll
        for (int t = 0; t < 3; ++t)
#pragma unroll
            for (int ksh = 0; ksh < 2; ++ksh)
                dst[t * 2 + ksh] =
                    gread16(Wb + ((size_t)(t * SL3 + c * 4 + wk * 2 + ksh) << 9));
    };

    // ---- accumulators: bias only on wk=0 (partials are summed later) ----
    f32x16 acc[4];
    const int rowA0 = wm * 128 + (lane & 31);
    const int coB   = wn * 32 + (lane & 31);
    {
        float bv = (wk == 0) ? bias[co0 + coB] : 0.f;
#pragma unroll
        for (int i = 0; i < 4; ++i)
#pragma unroll
            for (int r = 0; r < 16; ++r) acc[i][r] = bv;
    }

    short8 B0[6], B1[6];
    stageA(0, 0);
    __builtin_amdgcn_sched_barrier(0);
    loadB(B0, 0);
    __builtin_amdgcn_sched_barrier(0);
    asm volatile("s_waitcnt vmcnt(6)" ::: "memory");   // A(0) landed, B0 in flight
    __builtin_amdgcn_s_barrier();
    __builtin_amdgcn_sched_barrier(0);

    int cur = 0;
    auto kstep = [&](int c, short8* Bcur, short8* Bnxt) {
        if (c + 1 < NC) stageA(cur ^ 1, c + 1);
        __builtin_amdgcn_sched_barrier(0);

        // retire B(c); leave stage(c+1) in flight
        if (c + 1 < NC) asm volatile("s_waitcnt vmcnt(4)" ::: "memory");
        else            asm volatile("s_waitcnt vmcnt(0)" ::: "memory");
        __builtin_amdgcn_sched_barrier(0);        // rule 18: no MFMA hoist

        const short* As = &lds[cur][0];
        __builtin_amdgcn_s_setprio(1);
#pragma unroll
        for (int t = 0; t < 3; ++t) {
            const int shift = 16 + (t - 1) * rate;
#pragma unroll
            for (int ksh = 0; ksh < 2; ++ksh) {
                int ch = (wk * 2 + ksh) * 2 + (lane >> 5);
#pragma unroll
                for (int i = 0; i < 4; ++i) {
                    int rr = rowA0 + i * 32 + shift;
                    short8 av = *(const short8*)(As + rr * 64 + ((ch ^ (rr & 7)) << 3));
                    acc[i] = __builtin_amdgcn_mfma_f32_32x32x16_bf16(
                        av, Bcur[t * 2 + ksh], acc[i], 0, 0, 0);
                }
            }
        }
        __builtin_amdgcn_s_setprio(0);
        __builtin_amdgcn_sched_barrier(0);

        if (c + 1 < NC) {
            loadB(Bnxt, c + 1);
            __builtin_amdgcn_sched_barrier(0);
            asm volatile("s_waitcnt vmcnt(6)" ::: "memory");  // stage(c+1) retired
        }
        __builtin_amdgcn_s_barrier();
        cur ^= 1;
    };

    for (int c = 0; c < NC; c += 2) {
        kstep(c,     B0, B1);
        kstep(c + 1, B1, B0);
    }

    // ---- epilogue: wk=1 partials -> LDS; wk=0 adds, ReLU, bf16 store ----
    float* pf = (float*)&lds[0][0];               // 4 pairs x 16 KB = 64 KB
    const int pair = wm * 2 + wn;
    if (wk == 1) {
#pragma unroll
        for (int i = 0; i < 4; ++i)
#pragma unroll
            for (int r = 0; r < 16; ++r)
                pf[pair * 4096 + (i * 16 + r) * 64 + lane] = acc[i][r];
    }
    __syncthreads();
    if (wk == 0) {
        ushort_t* Yb = Yp + ((size_t)batch * PADN + HALO + n0) * HID + co0;
#pragma unroll
        for (int i = 0; i < 4; ++i) {
#pragma unroll
            for (int r = 0; r < 16; ++r) {
                int rrow = wm * 128 + i * 32 + (r & 3) + 8 * (r >> 2) + 4 * (lane >> 5);
                float v = acc[i][r] + pf[pair * 4096 + (i * 16 + r) * 64 + lane];
                v = v > 0.f ? v : 0.f;
                Yb[(size_t)rrow * HID + coB] = f2bf(v);
            }
        }
    }
}

// ---------------------------------------------------------------------------
// Offset head: out[p,:] = vertices[p,:] + h[p,:] @ w_off  (bf16 h, fp32 w)
// ---------------------------------------------------------------------------
__global__ __launch_bounds__(64) void head_kernel(
    const ushort_t* __restrict__ h, const float* __restrict__ w_off,
    const float* __restrict__ vertices, float* __restrict__ out)
{
    int p = blockIdx.x;
    int b = p >> 10, n = p & 1023;
    int t = threadIdx.x;
    const ushort_t* hr = h + ((size_t)b * PADN + HALO + n) * HID + t * 8;

    uint4 raw = *(const uint4*)hr;
    ushort_t hv[8];
    hv[0] = raw.x & 0xffff; hv[1] = raw.x >> 16;
    hv[2] = raw.y & 0xffff; hv[3] = raw.y >> 16;
    hv[4] = raw.z & 0xffff; hv[5] = raw.z >> 16;
    hv[6] = raw.w & 0xffff; hv[7] = raw.w >> 16;

    float s0 = 0.f, s1 = 0.f;
#pragma unroll
    for (int k = 0; k < 8; ++k) {
        float x = bf2f(hv[k]);
        s0 += x * w_off[(t * 8 + k) * 2 + 0];
        s1 += x * w_off[(t * 8 + k) * 2 + 1];
    }
#pragma unroll
    for (int off = 32; off >= 1; off >>= 1) {
        s0 += __shfl_down(s0, off);
        s1 += __shfl_down(s1, off);
    }
    if (t == 0) {
        out[2 * p + 0] = vertices[2 * p + 0] + s0;
        out[2 * p + 1] = vertices[2 * p + 1] + s1;
    }
}

// ---------------------------------------------------------------------------
extern "C" void kernel_launch(void* const* d_in, const int* in_sizes, int n_in,
                              void* d_out, int out_size, void* d_ws, size_t ws_size,
                              hipStream_t stream)
{
    (void)in_sizes; (void)n_in; (void)out_size; (void)ws_size;

    const float* vertices = (const float*)d_in[0];
    const float* features = (const float*)d_in[1];
    const float* w[6]  = {(const float*)d_in[2], (const float*)d_in[4],
                          (const float*)d_in[6], (const float*)d_in[8],
                          (const float*)d_in[10], (const float*)d_in[12]};
    const float* bb[6] = {(const float*)d_in[3], (const float*)d_in[5],
                          (const float*)d_in[7], (const float*)d_in[9],
                          (const float*)d_in[11], (const float*)d_in[13]};
    const float* w_off = (const float*)d_in[14];
    float* out = (float*)d_out;

    // ---- workspace layout ----
    char* p = (char*)d_ws;
    ushort_t* wt[6];
    wt[0] = (ushort_t*)p; p += (size_t)HID * (3 * FC) * 2;          // 768 KB
    for (int i = 1; i < 6; ++i) { wt[i] = (ushort_t*)p; p += (size_t)HID * (3 * HID) * 2; }
    ushort_t* XpA = (ushort_t*)p; p += (size_t)BATCH * PADN * FC  * 2;
    ushort_t* XpB = (ushort_t*)p; p += (size_t)BATCH * PADN * HID * 2;
    ushort_t* XpC = (ushort_t*)p;

    // ---- fused prep: halos + fragment-ordered weights + sampling ----
    prep_kernel<<<4384, 256, 0, stream>>>(
        vertices, features, w[0], w[1], w[2], w[3], w[4], w[5],
        wt[0], wt[1], wt[2], wt[3], wt[4], wt[5], XpA, XpB, XpC);

    // ---- conv stack (A -> B -> C -> B -> C -> B -> C) ----
    static const int rates[6] = {1, 3, 9, 9, 3, 1};
    conv_mfma<FC><<<256, 512, 0, stream>>>(XpA, wt[0], bb[0], XpB, rates[0]);
    ushort_t* src = XpB;
    ushort_t* dst = XpC;
    for (int i = 1; i < 6; ++i) {
        conv_mfma<HID><<<256, 512, 0, stream>>>(src, wt[i], bb[i], dst, rates[i]);
        ushort_t* tmp = src; src = dst; dst = tmp;
    }

    // ---- head ----
    head_kernel<<<BATCH * NPTS, 64, 0, stream>>>(src, w_off, vertices, out);
}